// Round 3
// baseline (500.075 us; speedup 1.0000x reference)
//
#include <hip/hip_runtime.h>
#include <math.h>

// HANLayer: semantic-attention tail is beta=softmax(scalar over size-1 axis)=1 -> output == GAT.
// Softmax shift-invariance: alpha = exp(e)/sum(exp(e)) exactly (e is O(1), no overflow risk),
// so no segment_max pass and no stored ee; denom accumulates in the same pass as the
// weighted feature sum. Pipeline: bf16 MFMA GEMM -> el/er -> degree hist -> scan ->
// CSR scatter -> per-node single-pass aggregation (+bias, elu).

#define NN 100000
#define NE 800000

typedef __attribute__((ext_vector_type(8))) short bf16x8;
typedef __attribute__((ext_vector_type(4))) float f32x4;

__device__ __forceinline__ unsigned short f2b(float f){
  unsigned u = __float_as_uint(f);
  return (unsigned short)((u + 0x7FFFu + ((u >> 16) & 1u)) >> 16);
}
__device__ __forceinline__ float b2f(unsigned short b){
  return __uint_as_float(((unsigned)b) << 16);
}

__global__ void k_init(int* __restrict__ cnt, int* __restrict__ cur){
  int i = blockIdx.x * 256 + threadIdx.x;
  if (i < NN){ cnt[i] = 0; cur[i] = 0; }
}

// W_fc[k][n] f32 -> Wt[n][k] bf16 (transposed so GEMM B-tile stages with row reads)
__global__ void k_prep(const float* __restrict__ W, unsigned short* __restrict__ Wt){
  int i = blockIdx.x * 256 + threadIdx.x;
  int n = i >> 8, k = i & 255;
  Wt[n * 256 + k] = f2b(W[k * 256 + n]);
}

// feat[M=100000][256] bf16 = h[M][256] @ W[256][256], tile BM=64 x BN=256, BK=32.
// 4 waves in 2x2, wave tile 32x128, mfma 16x16x32 bf16.
__global__ __launch_bounds__(256) void k_gemm(const float* __restrict__ A,
    const unsigned short* __restrict__ Wt, unsigned short* __restrict__ feat){
  __shared__ unsigned short lA[64][40];    // pad 32->40: 80B row stride, 16B-aligned
  __shared__ unsigned short lB[256][40];   // stored [n][k]
  const int t = threadIdx.x;
  const int lane = t & 63;
  const int wave = t >> 6;
  const int wm = wave >> 1, wn = wave & 1;
  const int bm = blockIdx.x * 64;
  const int l15 = lane & 15, lg = lane >> 4;

  f32x4 acc[2][8];
  #pragma unroll
  for (int i = 0; i < 2; ++i)
    #pragma unroll
    for (int j = 0; j < 8; ++j){ f32x4 z = {0.f,0.f,0.f,0.f}; acc[i][j] = z; }

  const int arow = t >> 2, ac8 = (t & 3) * 8;

  for (int kt = 0; kt < 8; ++kt){
    float4 a0 = {0,0,0,0}, a1 = {0,0,0,0};
    int gr = bm + arow;
    if (gr < NN){
      const float* p = A + (size_t)gr * 256 + kt * 32 + ac8;
      a0 = *(const float4*)p;
      a1 = *(const float4*)(p + 4);
    }
    uint4 bw[4];
    #pragma unroll
    for (int i = 0; i < 4; ++i){
      int c = i * 256 + t;
      bw[i] = *(const uint4*)(Wt + (c >> 2) * 256 + kt * 32 + (c & 3) * 8);
    }
    __syncthreads();
    {
      uint4 av;
      av.x = (unsigned)f2b(a0.x) | ((unsigned)f2b(a0.y) << 16);
      av.y = (unsigned)f2b(a0.z) | ((unsigned)f2b(a0.w) << 16);
      av.z = (unsigned)f2b(a1.x) | ((unsigned)f2b(a1.y) << 16);
      av.w = (unsigned)f2b(a1.z) | ((unsigned)f2b(a1.w) << 16);
      *(uint4*)&lA[arow][ac8] = av;
      #pragma unroll
      for (int i = 0; i < 4; ++i){
        int c = i * 256 + t;
        *(uint4*)&lB[c >> 2][(c & 3) * 8] = bw[i];
      }
    }
    __syncthreads();
    bf16x8 af0 = *(const bf16x8*)&lA[wm * 32 + l15][lg * 8];
    bf16x8 af1 = *(const bf16x8*)&lA[wm * 32 + 16 + l15][lg * 8];
    #pragma unroll
    for (int ni = 0; ni < 8; ++ni){
      bf16x8 bf = *(const bf16x8*)&lB[wn * 128 + ni * 16 + l15][lg * 8];
      acc[0][ni] = __builtin_amdgcn_mfma_f32_16x16x32_bf16(af0, bf, acc[0][ni], 0, 0, 0);
      acc[1][ni] = __builtin_amdgcn_mfma_f32_16x16x32_bf16(af1, bf, acc[1][ni], 0, 0, 0);
    }
  }
  // C layout: col = lane&15, row = 4*(lane>>4) + reg  [m89-verified]
  #pragma unroll
  for (int mi = 0; mi < 2; ++mi){
    #pragma unroll
    for (int ni = 0; ni < 8; ++ni){
      int c = wn * 128 + ni * 16 + l15;
      int r0 = bm + wm * 32 + mi * 16 + lg * 4;
      #pragma unroll
      for (int reg = 0; reg < 4; ++reg){
        int r = r0 + reg;
        if (r < NN) feat[(size_t)r * 256 + c] = f2b(acc[mi][ni][reg]);
      }
    }
  }
}

// el/er per (node,head): 32-elem dot of bf16 feat row with attn vectors
__global__ void k_elr(const unsigned short* __restrict__ feat,
                      const float* __restrict__ attn_l, const float* __restrict__ attn_r,
                      float* __restrict__ el, float* __restrict__ er){
  int i = blockIdx.x * 256 + threadIdx.x;
  if (i >= NN * 8) return;
  int h = i & 7;
  const unsigned short* f = feat + (size_t)i * 32;
  const float* al = attn_l + h * 32;
  const float* ar = attn_r + h * 32;
  float sl = 0.f, sr = 0.f;
  #pragma unroll
  for (int j = 0; j < 4; ++j){
    uint4 v = *(const uint4*)(f + j * 8);
    unsigned vv[4] = {v.x, v.y, v.z, v.w};
    #pragma unroll
    for (int q = 0; q < 4; ++q){
      float x0 = b2f((unsigned short)(vv[q] & 0xffffu));
      float x1 = b2f((unsigned short)(vv[q] >> 16));
      int d = j * 8 + q * 2;
      sl += x0 * al[d] + x1 * al[d + 1];
      sr += x0 * ar[d] + x1 * ar[d + 1];
    }
  }
  el[i] = sl; er[i] = sr;
}

// degree histogram only
__global__ void k_edge1(const int* __restrict__ dst, int* __restrict__ cnt){
  int e = blockIdx.x * 256 + threadIdx.x;
  if (e < NE) atomicAdd(&cnt[dst[e]], 1);
}

__global__ __launch_bounds__(1024) void k_scanA(const int* __restrict__ cnt,
    int* __restrict__ partial, int* __restrict__ bsum){
  __shared__ int lds[1024];
  int t = threadIdx.x;
  int i = blockIdx.x * 1024 + t;
  int v = (i < NN) ? cnt[i] : 0;
  lds[t] = v;
  __syncthreads();
  for (int off = 1; off < 1024; off <<= 1){
    int add = (t >= off) ? lds[t - off] : 0;
    __syncthreads();
    lds[t] += add;
    __syncthreads();
  }
  if (i < NN) partial[i] = lds[t] - v;   // exclusive within block
  if (t == 1023) bsum[blockIdx.x] = lds[1023];
}

__global__ void k_scanB(const int* __restrict__ bsum, int* __restrict__ boff, int nb){
  if (threadIdx.x == 0 && blockIdx.x == 0){
    int run = 0;
    for (int i = 0; i < nb; ++i){ boff[i] = run; run += bsum[i]; }
  }
}

// CSR slot scatter only
__global__ void k_edge2(const int* __restrict__ src, const int* __restrict__ dst,
                        const int* __restrict__ partial, const int* __restrict__ boff,
                        int* __restrict__ cur, int* __restrict__ csr_src){
  int e = blockIdx.x * 256 + threadIdx.x;
  if (e >= NE) return;
  int s = src[e], d = dst[e];
  int slot = partial[d] + boff[d >> 10] + atomicAdd(&cur[d], 1);
  csr_src[slot] = s;
}

// one wave per node (4 nodes/block): walk CSR, ee=exp(leaky(el[s]+er[n])) unshifted
// (softmax shift-invariant; |e| is O(1)), accumulate den and ee*feat in one pass,
// out = acc/den + bias -> elu.
__global__ __launch_bounds__(256) void k_agg(const int* __restrict__ csr_src,
    const float* __restrict__ el, const float* __restrict__ er,
    const unsigned short* __restrict__ feat, const int* __restrict__ partial,
    const int* __restrict__ boff, const float* __restrict__ bias, float* __restrict__ out){
  int n = blockIdx.x * 4 + (threadIdx.x >> 6);
  if (n >= NN) return;
  int t = threadIdx.x & 63;     // lane t covers elements 4t..4t+3 (head h = t>>3)
  int h = t >> 3;
  int beg = partial[n] + boff[n >> 10];
  int end = (n + 1 < NN) ? (partial[n + 1] + boff[(n + 1) >> 10]) : NE;
  float ern = er[(size_t)n * 8 + h];
  float den = 0.f, a0 = 0.f, a1 = 0.f, a2 = 0.f, a3 = 0.f;
  for (int i = beg; i < end; ++i){
    int s = csr_src[i];
    float e = el[(size_t)s * 8 + h] + ern;
    float x = e > 0.f ? e : 0.2f * e;
    float ee = __expf(x);
    den += ee;
    uint2 fv = *(const uint2*)(feat + (size_t)s * 256 + t * 4);
    a0 += ee * b2f((unsigned short)(fv.x & 0xffffu));
    a1 += ee * b2f((unsigned short)(fv.x >> 16));
    a2 += ee * b2f((unsigned short)(fv.y & 0xffffu));
    a3 += ee * b2f((unsigned short)(fv.y >> 16));
  }
  float inv = den > 0.f ? 1.f / den : 0.f;
  const float* bp = bias + t * 4;
  float4 o; float x;
  x = a0 * inv + bp[0]; o.x = x > 0.f ? x : expm1f(x);
  x = a1 * inv + bp[1]; o.y = x > 0.f ? x : expm1f(x);
  x = a2 * inv + bp[2]; o.z = x > 0.f ? x : expm1f(x);
  x = a3 * inv + bp[3]; o.w = x > 0.f ? x : expm1f(x);
  *(float4*)(out + (size_t)n * 256 + t * 4) = o;
}

extern "C" void kernel_launch(void* const* d_in, const int* in_sizes, int n_in,
                              void* d_out, int out_size, void* d_ws, size_t ws_size,
                              hipStream_t stream){
  (void)in_sizes; (void)n_in; (void)out_size; (void)ws_size;
  const float* h      = (const float*)d_in[0];
  const float* W_fc   = (const float*)d_in[1];
  const float* attn_l = (const float*)d_in[2];
  const float* attn_r = (const float*)d_in[3];
  const float* bias   = (const float*)d_in[4];
  // d_in[5..7] = sem_W1/sem_b1/sem_W2: provably no-op (beta == 1)
  const int* src = (const int*)d_in[8];
  const int* dst = (const int*)d_in[9];
  float* out = (float*)d_out;

  char* w = (char*)d_ws;
  auto alloc = [&](size_t b){ char* p = w; w += (b + 255) & ~(size_t)255; return p; };
  unsigned short* feat = (unsigned short*)alloc((size_t)NN * 256 * 2);   // 51.2 MB
  unsigned short* Wt   = (unsigned short*)alloc(256 * 256 * 2);
  float* el      = (float*)alloc((size_t)NN * 8 * 4);
  float* er      = (float*)alloc((size_t)NN * 8 * 4);
  int*   cnt     = (int*)alloc((size_t)NN * 4);
  int*   cur     = (int*)alloc((size_t)NN * 4);
  int*   partial = (int*)alloc((size_t)NN * 4);
  int*   bsum    = (int*)alloc(128 * 4);
  int*   boff    = (int*)alloc(128 * 4);
  int*   csr_src = (int*)alloc((size_t)NE * 4);                          // total ~62 MB

  const int nb = (NN + 1023) / 1024;

  k_init <<<(NN + 255) / 256, 256, 0, stream>>>(cnt, cur);
  k_prep <<<(256 * 256) / 256, 256, 0, stream>>>(W_fc, Wt);
  k_gemm <<<(NN + 63) / 64, 256, 0, stream>>>(h, Wt, feat);
  k_elr  <<<(NN * 8 + 255) / 256, 256, 0, stream>>>(feat, attn_l, attn_r, el, er);
  k_edge1<<<(NE + 255) / 256, 256, 0, stream>>>(dst, cnt);
  k_scanA<<<nb, 1024, 0, stream>>>(cnt, partial, bsum);
  k_scanB<<<1, 64, 0, stream>>>(bsum, boff, nb);
  k_edge2<<<(NE + 255) / 256, 256, 0, stream>>>(src, dst, partial, boff, cur, csr_src);
  k_agg  <<<(NN + 3) / 4, 256, 0, stream>>>(csr_src, el, er, feat, partial, boff, bias, out);
}

// Round 4
// 466.038 us; speedup vs baseline: 1.0730x; 1.0730x over previous
//
#include <hip/hip_runtime.h>
#include <math.h>

// HANLayer: semantic-attention tail is beta=softmax(scalar over size-1 axis)=1 -> output == GAT.
// Softmax shift-invariance: alpha = exp(e)/sum(exp(e)) (e is O(1), no overflow), so no
// segment_max pass; denom accumulates in the same pass as the weighted feature sum.
// R3 changes: k_agg 2-edges/wave + quad unroll (ILP), k_gemm software-pipelined staging,
// parallel scanB, init fused into prep.

#define NN 100000
#define NE 800000

typedef __attribute__((ext_vector_type(8))) short bf16x8;
typedef __attribute__((ext_vector_type(4))) float f32x4;

__device__ __forceinline__ unsigned short f2b(float f){
  unsigned u = __float_as_uint(f);
  return (unsigned short)((u + 0x7FFFu + ((u >> 16) & 1u)) >> 16);
}
__device__ __forceinline__ float b2f(unsigned short b){
  return __uint_as_float(((unsigned)b) << 16);
}

// Wt transpose+cast, and zero cnt/cur (fused init)
__global__ void k_prep(const float* __restrict__ W, unsigned short* __restrict__ Wt,
                       int* __restrict__ cnt, int* __restrict__ cur){
  int i = blockIdx.x * 256 + threadIdx.x;
  if (i < 65536){ int n = i >> 8, k = i & 255; Wt[n * 256 + k] = f2b(W[k * 256 + n]); }
  if (i < NN){ cnt[i] = 0; cur[i] = 0; }
}

// feat[100000][256] bf16 = h @ W_fc. BM=64 x BN=256, BK=32, 4 waves 2x2.
// Software-pipelined: global loads for kt+1 issue after the post-write barrier,
// hiding HBM latency under ds_read+MFMA of kt.
__global__ __launch_bounds__(256) void k_gemm(const float* __restrict__ A,
    const unsigned short* __restrict__ Wt, unsigned short* __restrict__ feat){
  __shared__ unsigned short lA[64][40];    // pad 32->40: 80B row stride, 16B-aligned
  __shared__ unsigned short lB[256][40];   // stored [n][k]
  const int t = threadIdx.x;
  const int lane = t & 63;
  const int wave = t >> 6;
  const int wm = wave >> 1, wn = wave & 1;
  const int bm = blockIdx.x * 64;
  const int l15 = lane & 15, lg = lane >> 4;

  f32x4 acc[2][8];
  #pragma unroll
  for (int i = 0; i < 2; ++i)
    #pragma unroll
    for (int j = 0; j < 8; ++j){ f32x4 z = {0.f,0.f,0.f,0.f}; acc[i][j] = z; }

  const int arow = t >> 2, ac8 = (t & 3) * 8;
  const int gr = bm + arow;

  float4 a0, a1; uint4 bw[4];
#define LOADG(KT) do {                                                        \
    float4 z4 = {0.f,0.f,0.f,0.f}; a0 = z4; a1 = z4;                          \
    if (gr < NN){                                                             \
      const float* p = A + (size_t)gr * 256 + (KT) * 32 + ac8;                \
      a0 = *(const float4*)p; a1 = *(const float4*)(p + 4);                   \
    }                                                                         \
    _Pragma("unroll")                                                         \
    for (int i_ = 0; i_ < 4; ++i_){                                           \
      int c = i_ * 256 + t;                                                   \
      bw[i_] = *(const uint4*)(Wt + (size_t)(c >> 2) * 256 + (KT) * 32 + (c & 3) * 8); \
    }                                                                         \
  } while (0)

  LOADG(0);
  for (int kt = 0; kt < 8; ++kt){
    __syncthreads();                     // prev iter's frag reads done
    {
      uint4 av;
      av.x = (unsigned)f2b(a0.x) | ((unsigned)f2b(a0.y) << 16);
      av.y = (unsigned)f2b(a0.z) | ((unsigned)f2b(a0.w) << 16);
      av.z = (unsigned)f2b(a1.x) | ((unsigned)f2b(a1.y) << 16);
      av.w = (unsigned)f2b(a1.z) | ((unsigned)f2b(a1.w) << 16);
      *(uint4*)&lA[arow][ac8] = av;
      #pragma unroll
      for (int i = 0; i < 4; ++i){
        int c = i * 256 + t;
        *(uint4*)&lB[c >> 2][(c & 3) * 8] = bw[i];
      }
    }
    __syncthreads();
    if (kt < 7) LOADG(kt + 1);           // prefetch next K-tile during MFMA phase
    bf16x8 af0 = *(const bf16x8*)&lA[wm * 32 + l15][lg * 8];
    bf16x8 af1 = *(const bf16x8*)&lA[wm * 32 + 16 + l15][lg * 8];
    #pragma unroll
    for (int ni = 0; ni < 8; ++ni){
      bf16x8 bf = *(const bf16x8*)&lB[wn * 128 + ni * 16 + l15][lg * 8];
      acc[0][ni] = __builtin_amdgcn_mfma_f32_16x16x32_bf16(af0, bf, acc[0][ni], 0, 0, 0);
      acc[1][ni] = __builtin_amdgcn_mfma_f32_16x16x32_bf16(af1, bf, acc[1][ni], 0, 0, 0);
    }
  }
#undef LOADG
  // C layout: col = lane&15, row = 4*(lane>>4) + reg  [m89-verified]
  #pragma unroll
  for (int mi = 0; mi < 2; ++mi){
    #pragma unroll
    for (int ni = 0; ni < 8; ++ni){
      int c = wn * 128 + ni * 16 + l15;
      int r0 = bm + wm * 32 + mi * 16 + lg * 4;
      #pragma unroll
      for (int reg = 0; reg < 4; ++reg){
        int r = r0 + reg;
        if (r < NN) feat[(size_t)r * 256 + c] = f2b(acc[mi][ni][reg]);
      }
    }
  }
}

// el/er per (node,head): 32-elem dot of bf16 feat row with attn vectors
__global__ void k_elr(const unsigned short* __restrict__ feat,
                      const float* __restrict__ attn_l, const float* __restrict__ attn_r,
                      float* __restrict__ el, float* __restrict__ er){
  int i = blockIdx.x * 256 + threadIdx.x;
  if (i >= NN * 8) return;
  int h = i & 7;
  const unsigned short* f = feat + (size_t)i * 32;
  const float* al = attn_l + h * 32;
  const float* ar = attn_r + h * 32;
  float sl = 0.f, sr = 0.f;
  #pragma unroll
  for (int j = 0; j < 4; ++j){
    uint4 v = *(const uint4*)(f + j * 8);
    unsigned vv[4] = {v.x, v.y, v.z, v.w};
    #pragma unroll
    for (int q = 0; q < 4; ++q){
      float x0 = b2f((unsigned short)(vv[q] & 0xffffu));
      float x1 = b2f((unsigned short)(vv[q] >> 16));
      int d = j * 8 + q * 2;
      sl += x0 * al[d] + x1 * al[d + 1];
      sr += x0 * ar[d] + x1 * ar[d + 1];
    }
  }
  el[i] = sl; er[i] = sr;
}

// degree histogram
__global__ void k_edge1(const int* __restrict__ dst, int* __restrict__ cnt){
  int e = blockIdx.x * 256 + threadIdx.x;
  if (e < NE) atomicAdd(&cnt[dst[e]], 1);
}

__global__ __launch_bounds__(1024) void k_scanA(const int* __restrict__ cnt,
    int* __restrict__ partial, int* __restrict__ bsum){
  __shared__ int lds[1024];
  int t = threadIdx.x;
  int i = blockIdx.x * 1024 + t;
  int v = (i < NN) ? cnt[i] : 0;
  lds[t] = v;
  __syncthreads();
  for (int off = 1; off < 1024; off <<= 1){
    int add = (t >= off) ? lds[t - off] : 0;
    __syncthreads();
    lds[t] += add;
    __syncthreads();
  }
  if (i < NN) partial[i] = lds[t] - v;   // exclusive within block
  if (t == 1023) bsum[blockIdx.x] = lds[1023];
}

// parallel exclusive scan over <=128 block sums (was serial single-thread loop)
__global__ __launch_bounds__(128) void k_scanB(const int* __restrict__ bsum,
                                               int* __restrict__ boff, int nb){
  __shared__ int lds[128];
  int t = threadIdx.x;
  int v = (t < nb) ? bsum[t] : 0;
  lds[t] = v;
  __syncthreads();
  for (int off = 1; off < 128; off <<= 1){
    int add = (t >= off) ? lds[t - off] : 0;
    __syncthreads();
    lds[t] += add;
    __syncthreads();
  }
  if (t < nb) boff[t] = lds[t] - v;
}

// CSR slot scatter
__global__ void k_edge2(const int* __restrict__ src, const int* __restrict__ dst,
                        const int* __restrict__ partial, const int* __restrict__ boff,
                        int* __restrict__ cur, int* __restrict__ csr_src){
  int e = blockIdx.x * 256 + threadIdx.x;
  if (e >= NE) return;
  int s = src[e], d = dst[e];
  int slot = partial[d] + boff[d >> 10] + atomicAdd(&cur[d], 1);
  csr_src[slot] = s;
}

__device__ __forceinline__ void acc8(float* a, uint4 f, float w){
  unsigned u[4] = {f.x, f.y, f.z, f.w};
  #pragma unroll
  for (int j = 0; j < 4; ++j){
    a[2 * j]     += w * __uint_as_float(u[j] << 16);
    a[2 * j + 1] += w * __uint_as_float(u[j] & 0xffff0000u);
  }
}

// one wave per node, 4 nodes/block. Two edges per wave (half-wave each, uint4 16B/lane),
// quad-unrolled main loop -> 4 feat rows (2KB) in flight. Cross-half shfl_xor(32) reduce.
__global__ __launch_bounds__(256) void k_agg(const int* __restrict__ csr_src,
    const float* __restrict__ el, const float* __restrict__ er,
    const unsigned short* __restrict__ feat, const int* __restrict__ partial,
    const int* __restrict__ boff, const float* __restrict__ bias, float* __restrict__ out){
  int n = blockIdx.x * 4 + (threadIdx.x >> 6);
  if (n >= NN) return;
  const int t = threadIdx.x & 63;
  const int half = t >> 5;         // which edge of the pair this lane serves
  const int q = t & 31;            // covers elems 8q..8q+7 of the 256-wide row
  const int h = q >> 2;            // head = (8q)>>5
  int beg = partial[n] + boff[n >> 10];
  int end = (n + 1 < NN) ? (partial[n + 1] + boff[(n + 1) >> 10]) : NE;
  float ern = er[(size_t)n * 8 + h];
  float den = 0.f;
  float a[8] = {0.f,0.f,0.f,0.f,0.f,0.f,0.f,0.f};
  const unsigned short* fb = feat + q * 8;   // lane-constant element offset

  int i = beg;
  for (; i + 4 <= end; i += 4){    // 4 valid edges, no guards
    int s0 = csr_src[i + half];
    int s1 = csr_src[i + 2 + half];
    uint4 f0 = *(const uint4*)(fb + (size_t)s0 * 256);
    uint4 f1 = *(const uint4*)(fb + (size_t)s1 * 256);
    float e0 = el[(size_t)s0 * 8 + h] + ern;
    float e1 = el[(size_t)s1 * 8 + h] + ern;
    e0 = e0 > 0.f ? e0 : 0.2f * e0;  e0 = __expf(e0);
    e1 = e1 > 0.f ? e1 : 0.2f * e1;  e1 = __expf(e1);
    den += e0 + e1;
    acc8(a, f0, e0);
    acc8(a, f1, e1);
  }
  for (; i < end; i += 2){         // remainder (<=3 edges), guarded per half
    int ia = i + half;
    if (ia < end){
      int s = csr_src[ia];
      uint4 f = *(const uint4*)(fb + (size_t)s * 256);
      float e = el[(size_t)s * 8 + h] + ern;
      e = e > 0.f ? e : 0.2f * e;  e = __expf(e);
      den += e;
      acc8(a, f, e);
    }
  }
  // combine the two half-wave edge streams
  den += __shfl_xor(den, 32);
  #pragma unroll
  for (int j = 0; j < 8; ++j) a[j] += __shfl_xor(a[j], 32);
  float inv = den > 0.f ? 1.f / den : 0.f;

  // lane(half=0) writes elems 8q..8q+3, half=1 writes 8q+4..8q+7 (fully coalesced 1KB/row)
  const float* bp = bias + q * 8 + half * 4;
  float4 o;
  #pragma unroll
  for (int j = 0; j < 4; ++j){
    float v = (half ? a[4 + j] : a[j]) * inv + bp[j];   // static indices (no scratch)
    ((float*)&o)[j] = v > 0.f ? v : expm1f(v);
  }
  *(float4*)(out + (size_t)n * 256 + q * 8 + half * 4) = o;
}

extern "C" void kernel_launch(void* const* d_in, const int* in_sizes, int n_in,
                              void* d_out, int out_size, void* d_ws, size_t ws_size,
                              hipStream_t stream){
  (void)in_sizes; (void)n_in; (void)out_size; (void)ws_size;
  const float* h      = (const float*)d_in[0];
  const float* W_fc   = (const float*)d_in[1];
  const float* attn_l = (const float*)d_in[2];
  const float* attn_r = (const float*)d_in[3];
  const float* bias   = (const float*)d_in[4];
  // d_in[5..7] = sem_W1/sem_b1/sem_W2: provably no-op (beta == 1)
  const int* src = (const int*)d_in[8];
  const int* dst = (const int*)d_in[9];
  float* out = (float*)d_out;

  char* w = (char*)d_ws;
  auto alloc = [&](size_t b){ char* p = w; w += (b + 255) & ~(size_t)255; return p; };
  unsigned short* feat = (unsigned short*)alloc((size_t)NN * 256 * 2);   // 51.2 MB
  unsigned short* Wt   = (unsigned short*)alloc(256 * 256 * 2);
  float* el      = (float*)alloc((size_t)NN * 8 * 4);
  float* er      = (float*)alloc((size_t)NN * 8 * 4);
  int*   cnt     = (int*)alloc((size_t)NN * 4);
  int*   cur     = (int*)alloc((size_t)NN * 4);
  int*   partial = (int*)alloc((size_t)NN * 4);
  int*   bsum    = (int*)alloc(128 * 4);
  int*   boff    = (int*)alloc(128 * 4);
  int*   csr_src = (int*)alloc((size_t)NE * 4);                          // total ~62 MB

  const int nb = (NN + 1023) / 1024;

  k_prep <<<(NN + 255) / 256, 256, 0, stream>>>(W_fc, Wt, cnt, cur);
  k_gemm <<<(NN + 63) / 64, 256, 0, stream>>>(h, Wt, feat);
  k_elr  <<<(NN * 8 + 255) / 256, 256, 0, stream>>>(feat, attn_l, attn_r, el, er);
  k_edge1<<<(NE + 255) / 256, 256, 0, stream>>>(dst, cnt);
  k_scanA<<<nb, 1024, 0, stream>>>(cnt, partial, bsum);
  k_scanB<<<1, 128, 0, stream>>>(bsum, boff, nb);
  k_edge2<<<(NE + 255) / 256, 256, 0, stream>>>(src, dst, partial, boff, cur, csr_src);
  k_agg  <<<(NN + 3) / 4, 256, 0, stream>>>(csr_src, el, er, feat, partial, boff, bias, out);
}

// Round 5
// 419.134 us; speedup vs baseline: 1.1931x; 1.1119x over previous
//
#include <hip/hip_runtime.h>
#include <math.h>

// HANLayer: semantic-attention tail is beta=softmax(scalar over size-1 axis)=1 -> output == GAT.
// Softmax shift-invariance: alpha = exp(e)/sum(exp(e)) (e is O(1), no overflow), so no
// segment_max pass; denom accumulates in the same pass as the weighted feature sum.
// R4: k_gemm rewritten — A-frags global->reg (coalesced 64B, no LDS, no staging barriers),
// B-half (256x128 bf16 = 64KB) LDS-resident with XOR swizzle (conflict-free ds_read_b128),
// K-loop has ZERO barriers; 3 barriers/block total. Everything else unchanged from R3.

#define NN 100000
#define NE 800000

typedef __attribute__((ext_vector_type(8))) short bf16x8;
typedef __attribute__((ext_vector_type(4))) float f32x4;

__device__ __forceinline__ unsigned short f2b(float f){
  unsigned u = __float_as_uint(f);
  return (unsigned short)((u + 0x7FFFu + ((u >> 16) & 1u)) >> 16);
}
__device__ __forceinline__ float b2f(unsigned short b){
  return __uint_as_float(((unsigned)b) << 16);
}

// Wt transpose+cast, and zero cnt/cur (fused init)
__global__ void k_prep(const float* __restrict__ W, unsigned short* __restrict__ Wt,
                       int* __restrict__ cnt, int* __restrict__ cur){
  int i = blockIdx.x * 256 + threadIdx.x;
  if (i < 65536){ int n = i >> 8, k = i & 255; Wt[n * 256 + k] = f2b(W[k * 256 + n]); }
  if (i < NN){ cnt[i] = 0; cur[i] = 0; }
}

// feat[100000][256] bf16 = h @ W_fc.  BM=128 (4 waves x 32 rows), N processed in two
// 128-col halves. B-half in LDS (64KB), XOR-swizzled granules: byte = n*512 + ((s^(n&31))<<4)
// where s = k/8. A-frags live in registers for all 8 k-tiles. K-loop barrier-free.
__global__ __launch_bounds__(256) void k_gemm(const float* __restrict__ A,
    const unsigned short* __restrict__ Wt, unsigned short* __restrict__ feat){
  __shared__ unsigned short lB[32768];           // 64 KB: [n<128][k<256] swizzled
  const int t = threadIdx.x;
  const int lane = t & 63;
  const int wave = t >> 6;
  const int l15 = lane & 15, lg = lane >> 4;
  const int bm = blockIdx.x * 128;
  const int m0 = bm + wave * 32;

  // ---- A fragments: 8 k-tiles x 2 row-groups, direct global->reg, RTNE to bf16 ----
  bf16x8 afr[8][2];
  #pragma unroll
  for (int kt = 0; kt < 8; ++kt){
    #pragma unroll
    for (int mi = 0; mi < 2; ++mi){
      int r = m0 + mi * 16 + l15;
      float4 x = {0.f,0.f,0.f,0.f}, y = x;
      if (r < NN){
        const float* p = A + (size_t)r * 256 + kt * 32 + lg * 8;
        x = *(const float4*)p; y = *(const float4*)(p + 4);
      }
      union { bf16x8 v; unsigned u[4]; } pk;
      pk.u[0] = (unsigned)f2b(x.x) | ((unsigned)f2b(x.y) << 16);
      pk.u[1] = (unsigned)f2b(x.z) | ((unsigned)f2b(x.w) << 16);
      pk.u[2] = (unsigned)f2b(y.x) | ((unsigned)f2b(y.y) << 16);
      pk.u[3] = (unsigned)f2b(y.z) | ((unsigned)f2b(y.w) << 16);
      afr[kt][mi] = pk.v;
    }
  }

  for (int c = 0; c < 2; ++c){
    if (c) __syncthreads();                      // all waves done reading half 0
    // ---- stage B-half c: 4096 granules of 16B, swizzled ----
    #pragma unroll
    for (int i = 0; i < 16; ++i){
      int flat = i * 256 + t;                    // granule index
      int n = flat >> 5, s = flat & 31;
      uint4 v = *(const uint4*)(Wt + (((size_t)(c * 128 + n)) << 8) + s * 8);
      *(uint4*)((char*)lB + n * 512 + ((s ^ (n & 31)) << 4)) = v;
    }
    __syncthreads();

    f32x4 acc[2][8];
    #pragma unroll
    for (int i = 0; i < 2; ++i)
      #pragma unroll
      for (int j = 0; j < 8; ++j){ f32x4 z = {0.f,0.f,0.f,0.f}; acc[i][j] = z; }

    #pragma unroll
    for (int kt = 0; kt < 8; ++kt){
      #pragma unroll
      for (int ni = 0; ni < 8; ++ni){
        int n = ni * 16 + l15;
        int s = kt * 4 + lg;
        bf16x8 bfr = *(const bf16x8*)((char*)lB + n * 512 + ((s ^ (n & 31)) << 4));
        acc[0][ni] = __builtin_amdgcn_mfma_f32_16x16x32_bf16(afr[kt][0], bfr, acc[0][ni], 0, 0, 0);
        acc[1][ni] = __builtin_amdgcn_mfma_f32_16x16x32_bf16(afr[kt][1], bfr, acc[1][ni], 0, 0, 0);
      }
    }
    // C layout: col = lane&15, row = 4*(lane>>4) + reg  [m89-verified]
    #pragma unroll
    for (int mi = 0; mi < 2; ++mi){
      #pragma unroll
      for (int ni = 0; ni < 8; ++ni){
        int col = c * 128 + ni * 16 + l15;
        int r0 = m0 + mi * 16 + lg * 4;
        #pragma unroll
        for (int reg = 0; reg < 4; ++reg){
          int r = r0 + reg;
          if (r < NN) feat[(size_t)r * 256 + col] = f2b(acc[mi][ni][reg]);
        }
      }
    }
  }
}

// el/er per (node,head): 32-elem dot of bf16 feat row with attn vectors
__global__ void k_elr(const unsigned short* __restrict__ feat,
                      const float* __restrict__ attn_l, const float* __restrict__ attn_r,
                      float* __restrict__ el, float* __restrict__ er){
  int i = blockIdx.x * 256 + threadIdx.x;
  if (i >= NN * 8) return;
  int h = i & 7;
  const unsigned short* f = feat + (size_t)i * 32;
  const float* al = attn_l + h * 32;
  const float* ar = attn_r + h * 32;
  float sl = 0.f, sr = 0.f;
  #pragma unroll
  for (int j = 0; j < 4; ++j){
    uint4 v = *(const uint4*)(f + j * 8);
    unsigned vv[4] = {v.x, v.y, v.z, v.w};
    #pragma unroll
    for (int q = 0; q < 4; ++q){
      float x0 = b2f((unsigned short)(vv[q] & 0xffffu));
      float x1 = b2f((unsigned short)(vv[q] >> 16));
      int d = j * 8 + q * 2;
      sl += x0 * al[d] + x1 * al[d + 1];
      sr += x0 * ar[d] + x1 * ar[d + 1];
    }
  }
  el[i] = sl; er[i] = sr;
}

// degree histogram
__global__ void k_edge1(const int* __restrict__ dst, int* __restrict__ cnt){
  int e = blockIdx.x * 256 + threadIdx.x;
  if (e < NE) atomicAdd(&cnt[dst[e]], 1);
}

__global__ __launch_bounds__(1024) void k_scanA(const int* __restrict__ cnt,
    int* __restrict__ partial, int* __restrict__ bsum){
  __shared__ int lds[1024];
  int t = threadIdx.x;
  int i = blockIdx.x * 1024 + t;
  int v = (i < NN) ? cnt[i] : 0;
  lds[t] = v;
  __syncthreads();
  for (int off = 1; off < 1024; off <<= 1){
    int add = (t >= off) ? lds[t - off] : 0;
    __syncthreads();
    lds[t] += add;
    __syncthreads();
  }
  if (i < NN) partial[i] = lds[t] - v;   // exclusive within block
  if (t == 1023) bsum[blockIdx.x] = lds[1023];
}

// parallel exclusive scan over <=128 block sums
__global__ __launch_bounds__(128) void k_scanB(const int* __restrict__ bsum,
                                               int* __restrict__ boff, int nb){
  __shared__ int lds[128];
  int t = threadIdx.x;
  int v = (t < nb) ? bsum[t] : 0;
  lds[t] = v;
  __syncthreads();
  for (int off = 1; off < 128; off <<= 1){
    int add = (t >= off) ? lds[t - off] : 0;
    __syncthreads();
    lds[t] += add;
    __syncthreads();
  }
  if (t < nb) boff[t] = lds[t] - v;
}

// CSR slot scatter
__global__ void k_edge2(const int* __restrict__ src, const int* __restrict__ dst,
                        const int* __restrict__ partial, const int* __restrict__ boff,
                        int* __restrict__ cur, int* __restrict__ csr_src){
  int e = blockIdx.x * 256 + threadIdx.x;
  if (e >= NE) return;
  int s = src[e], d = dst[e];
  int slot = partial[d] + boff[d >> 10] + atomicAdd(&cur[d], 1);
  csr_src[slot] = s;
}

__device__ __forceinline__ void acc8(float* a, uint4 f, float w){
  unsigned u[4] = {f.x, f.y, f.z, f.w};
  #pragma unroll
  for (int j = 0; j < 4; ++j){
    a[2 * j]     += w * __uint_as_float(u[j] << 16);
    a[2 * j + 1] += w * __uint_as_float(u[j] & 0xffff0000u);
  }
}

// one wave per node, 4 nodes/block. Two edges per wave (half-wave each, uint4 16B/lane),
// quad-unrolled main loop -> 4 feat rows (2KB) in flight. Cross-half shfl_xor(32) reduce.
__global__ __launch_bounds__(256) void k_agg(const int* __restrict__ csr_src,
    const float* __restrict__ el, const float* __restrict__ er,
    const unsigned short* __restrict__ feat, const int* __restrict__ partial,
    const int* __restrict__ boff, const float* __restrict__ bias, float* __restrict__ out){
  int n = blockIdx.x * 4 + (threadIdx.x >> 6);
  if (n >= NN) return;
  const int t = threadIdx.x & 63;
  const int half = t >> 5;         // which edge of the pair this lane serves
  const int q = t & 31;            // covers elems 8q..8q+7 of the 256-wide row
  const int h = q >> 2;            // head = (8q)>>5
  int beg = partial[n] + boff[n >> 10];
  int end = (n + 1 < NN) ? (partial[n + 1] + boff[(n + 1) >> 10]) : NE;
  float ern = er[(size_t)n * 8 + h];
  float den = 0.f;
  float a[8] = {0.f,0.f,0.f,0.f,0.f,0.f,0.f,0.f};
  const unsigned short* fb = feat + q * 8;   // lane-constant element offset

  int i = beg;
  for (; i + 4 <= end; i += 4){    // 4 valid edges, no guards
    int s0 = csr_src[i + half];
    int s1 = csr_src[i + 2 + half];
    uint4 f0 = *(const uint4*)(fb + (size_t)s0 * 256);
    uint4 f1 = *(const uint4*)(fb + (size_t)s1 * 256);
    float e0 = el[(size_t)s0 * 8 + h] + ern;
    float e1 = el[(size_t)s1 * 8 + h] + ern;
    e0 = e0 > 0.f ? e0 : 0.2f * e0;  e0 = __expf(e0);
    e1 = e1 > 0.f ? e1 : 0.2f * e1;  e1 = __expf(e1);
    den += e0 + e1;
    acc8(a, f0, e0);
    acc8(a, f1, e1);
  }
  for (; i < end; i += 2){         // remainder (<=3 edges), guarded per half
    int ia = i + half;
    if (ia < end){
      int s = csr_src[ia];
      uint4 f = *(const uint4*)(fb + (size_t)s * 256);
      float e = el[(size_t)s * 8 + h] + ern;
      e = e > 0.f ? e : 0.2f * e;  e = __expf(e);
      den += e;
      acc8(a, f, e);
    }
  }
  // combine the two half-wave edge streams
  den += __shfl_xor(den, 32);
  #pragma unroll
  for (int j = 0; j < 8; ++j) a[j] += __shfl_xor(a[j], 32);
  float inv = den > 0.f ? 1.f / den : 0.f;

  // lane(half=0) writes elems 8q..8q+3, half=1 writes 8q+4..8q+7 (fully coalesced 1KB/row)
  const float* bp = bias + q * 8 + half * 4;
  float4 o;
  #pragma unroll
  for (int j = 0; j < 4; ++j){
    float v = (half ? a[4 + j] : a[j]) * inv + bp[j];   // static indices (no scratch)
    ((float*)&o)[j] = v > 0.f ? v : expm1f(v);
  }
  *(float4*)(out + (size_t)n * 256 + q * 8 + half * 4) = o;
}

extern "C" void kernel_launch(void* const* d_in, const int* in_sizes, int n_in,
                              void* d_out, int out_size, void* d_ws, size_t ws_size,
                              hipStream_t stream){
  (void)in_sizes; (void)n_in; (void)out_size; (void)ws_size;
  const float* h      = (const float*)d_in[0];
  const float* W_fc   = (const float*)d_in[1];
  const float* attn_l = (const float*)d_in[2];
  const float* attn_r = (const float*)d_in[3];
  const float* bias   = (const float*)d_in[4];
  // d_in[5..7] = sem_W1/sem_b1/sem_W2: provably no-op (beta == 1)
  const int* src = (const int*)d_in[8];
  const int* dst = (const int*)d_in[9];
  float* out = (float*)d_out;

  char* w = (char*)d_ws;
  auto alloc = [&](size_t b){ char* p = w; w += (b + 255) & ~(size_t)255; return p; };
  unsigned short* feat = (unsigned short*)alloc((size_t)NN * 256 * 2);   // 51.2 MB
  unsigned short* Wt   = (unsigned short*)alloc(256 * 256 * 2);
  float* el      = (float*)alloc((size_t)NN * 8 * 4);
  float* er      = (float*)alloc((size_t)NN * 8 * 4);
  int*   cnt     = (int*)alloc((size_t)NN * 4);
  int*   cur     = (int*)alloc((size_t)NN * 4);
  int*   partial = (int*)alloc((size_t)NN * 4);
  int*   bsum    = (int*)alloc(128 * 4);
  int*   boff    = (int*)alloc(128 * 4);
  int*   csr_src = (int*)alloc((size_t)NE * 4);                          // total ~62 MB

  const int nb = (NN + 1023) / 1024;

  k_prep <<<(NN + 255) / 256, 256, 0, stream>>>(W_fc, Wt, cnt, cur);
  k_gemm <<<(NN + 127) / 128, 256, 0, stream>>>(h, Wt, feat);
  k_elr  <<<(NN * 8 + 255) / 256, 256, 0, stream>>>(feat, attn_l, attn_r, el, er);
  k_edge1<<<(NE + 255) / 256, 256, 0, stream>>>(dst, cnt);
  k_scanA<<<nb, 1024, 0, stream>>>(cnt, partial, bsum);
  k_scanB<<<1, 128, 0, stream>>>(bsum, boff, nb);
  k_edge2<<<(NE + 255) / 256, 256, 0, stream>>>(src, dst, partial, boff, cur, csr_src);
  k_agg  <<<(NN + 3) / 4, 256, 0, stream>>>(csr_src, el, er, feat, partial, boff, bias, out);
}